// Round 9
// baseline (289.148 us; speedup 1.0000x reference)
//
#include <hip/hip_runtime.h>

#define BINS 10

// R13: R12 resubmit with the compile fix. __builtin_nontemporal_load rejects
// HIP_vector_type<float,4>*; use a clang ext_vector_type(4) alias (identical
// 16B layout/alignment) for the nt loads. Theory unchanged: 268 MB working
// set vs 256 MB Infinity Cache = LLC LRU thrash (FETCH ~131 MB = half split
// every pass, 2.35 TB/s effective vs 2.85 proven / 6.3 copy). nt loads
// (no-allocate) stop the churn and stream from HBM. Diagnostic: FETCH_SIZE
// must jump to ~268 MB. Math untouched -> absmax 0.0.

typedef float vf4 __attribute__((ext_vector_type(4)));

__device__ __forceinline__ vf4 ntload(const vf4* __restrict__ a)
{
    return __builtin_nontemporal_load(a);
}

__device__ __forceinline__ void elem(float p, float t,
                                     float* __restrict__ sb,
                                     unsigned int* __restrict__ cw)
{
    float g  = fabsf(p - t);
    float l2 = __log2f(1.0f - g);     // bce = -ln2*log2(1-g); fold -ln2 at end
    int   bi = (int)(g * 10.0f);      // g in (0.01,0.99): bi in [0,9]
#pragma unroll
    for (int b = 0; b < BINS; ++b) {
        bool hit = (bi == b);                   // one v_cmp -> sgpr pair
        unsigned long long m = __ballot(hit);   // reuses the compare
        sb[b] += hit ? l2 : 0.0f;               // cndmask + add (VALU)
        cw[b] += (unsigned int)__popcll(m);     // scalar pipe (wave-uniform)
    }
}

__device__ __forceinline__ void proc4v(const vf4 p, const vf4 t,
                                       float* __restrict__ sb,
                                       unsigned int* __restrict__ cw)
{
    elem(p.x, t.x, sb, cw); elem(p.y, t.y, sb, cw);
    elem(p.z, t.z, sb, cw); elem(p.w, t.w, sb, cw);
}

__global__ __launch_bounds__(256, 8) void ghm_partial(
    const vf4* __restrict__ p4,
    const vf4* __restrict__ t4,
    float* __restrict__ gsum,          // [BINS] floats in d_ws
    unsigned int* __restrict__ gcnt,   // [BINS] uints in d_ws
    int n4)
{
    float        sb[BINS];
    unsigned int cw[BINS];
#pragma unroll
    for (int b = 0; b < BINS; ++b) { sb[b] = 0.0f; cw[b] = 0u; }

    const int tid    = threadIdx.x;
    const int start  = blockIdx.x * blockDim.x + tid;
    const int stride = gridDim.x * blockDim.x;
    const int ngrp   = n4 / (4 * stride);   // 4 at 2048x256, n4 = 2^23

    // Bulk-load groups: 8 interleaved dwordx4 nt-loads (128 B/thread in
    // flight), then a scheduling fence so loads cannot sink into compute.
    int i = start;
    for (int grp = 0; grp < ngrp; ++grp, i += 4 * stride) {
        vf4 P0 = ntload(p4 + i);
        vf4 T0 = ntload(t4 + i);
        vf4 P1 = ntload(p4 + i + stride);
        vf4 T1 = ntload(t4 + i + stride);
        vf4 P2 = ntload(p4 + i + 2 * stride);
        vf4 T2 = ntload(t4 + i + 2 * stride);
        vf4 P3 = ntload(p4 + i + 3 * stride);
        vf4 T3 = ntload(t4 + i + 3 * stride);
        __builtin_amdgcn_sched_barrier(0);  // loads above, compute below
        proc4v(P0, T0, sb, cw);
        proc4v(P1, T1, sb, cw);
        proc4v(P2, T2, sb, cw);
        proc4v(P3, T3, sb, cw);
    }
    // tail: any remaining float4s (n4 not divisible by 4*stride)
    for (int j = start + ngrp * 4 * stride; j < n4; j += stride) {
        vf4 p = ntload(p4 + j), t = ntload(t4 + j);
        proc4v(p, t, sb, cw);
    }

    // -------- epilogue: wave reduce -> LDS -> one global atomic/bin/block ----
    __shared__ float        redS[BINS];
    __shared__ unsigned int redC[BINS];
    if (tid < BINS) { redS[tid] = 0.0f; redC[tid] = 0u; }
    __syncthreads();

    const int lane = tid & 63;
#pragma unroll
    for (int b = 0; b < BINS; ++b) {
        float s = sb[b];
#pragma unroll
        for (int off = 32; off > 0; off >>= 1) s += __shfl_down(s, off);
        if (lane == 0) {
            atomicAdd(&redS[b], s);
            atomicAdd(&redC[b], cw[b]);   // cw is wave-uniform (ballot-derived)
        }
    }
    __syncthreads();
    if (tid < BINS) {
        atomicAdd(&gsum[tid], redS[tid]);
        atomicAdd(&gcnt[tid], redC[tid]);
    }
}

__global__ void ghm_finalize(const float* __restrict__ gsum,
                             const unsigned int* __restrict__ gcnt,
                             float* __restrict__ out)
{
    if (threadIdx.x == 0 && blockIdx.x == 0) {
        int n = 0;
#pragma unroll
        for (int b = 0; b < BINS; ++b) n += (gcnt[b] > 0u) ? 1 : 0;
        float nn = (float)(n > 0 ? n : 1);
        float acc = 0.0f;
#pragma unroll
        for (int b = 0; b < BINS; ++b) {
            if (gcnt[b] > 0u)
                acc += gsum[b] / ((float)gcnt[b] * nn);  // counts < 2^24: exact
        }
        out[0] = -0.6931471805599453f * acc;   // fold -ln(2) from log2 domain
    }
}

extern "C" void kernel_launch(void* const* d_in, const int* in_sizes, int n_in,
                              void* d_out, int out_size, void* d_ws, size_t ws_size,
                              hipStream_t stream)
{
    const float* p = (const float*)d_in[0];   // inputs (probabilities)
    const float* t = (const float*)d_in[1];   // targets (0/1 floats)
    const int n  = in_sizes[0];               // 262144*128
    const int n4 = n >> 2;                    // divisible by 4

    float*        gsum = (float*)d_ws;
    unsigned int* gcnt = (unsigned int*)((char*)d_ws + BINS * sizeof(float));

    // d_ws is re-poisoned to 0xAA before every timed launch — zero it (capturable)
    (void)hipMemsetAsync(d_ws, 0, BINS * (sizeof(float) + sizeof(unsigned int)), stream);

    const int threads = 256;
    const int blocks  = 2048;   // 16 float4/thread -> 4 bulk groups
    ghm_partial<<<blocks, threads, 0, stream>>>(
        (const vf4*)p, (const vf4*)t, gsum, gcnt, n4);

    ghm_finalize<<<1, 64, 0, stream>>>(gsum, gcnt, (float*)d_out);
}